// Round 4
// baseline (465.303 us; speedup 1.0000x reference)
//
#include <hip/hip_runtime.h>

// RAFilter: I_RA[t] = a*I_RA[t-1] + c*|I[t]-I[t-1]|, I[-1]=0, I_RA[-1]=0
// a = 1 - DT/TAU = 0.99666667, c = K3/TAU = 0.06666667 (DT cancels).
// Shapes (B=8, T=4096, N=2048) fp32.
//
// Two-pass segmented scan: T split into SEG=16 segments of L=256.
// Block = 64 chains x 16 segment-waves = 1024 threads; 256 blocks -> 16 waves/CU.
// Pass A: per-wave segment end-state E_s (read-only). Carry combine via LDS:
// S_j = E_j + A*S_{j-1}, A = a^L. Pass B: exact recurrence re-run with
// state=carry, writes output. Traffic ~768MB -> ~120us floor @6.3TB/s.

constexpr int Bb  = 8;
constexpr int Tn  = 4096;
constexpr int Nn  = 2048;
constexpr int SEG = 16;
constexpr int L   = Tn / SEG;   // 256
constexpr int U   = 16;         // prefetch chunk

__global__ __launch_bounds__(64 * SEG) void ra_filter2_kernel(
    const float* __restrict__ in, float* __restrict__ out) {
    const int lane = threadIdx.x & 63;
    const int s    = threadIdx.x >> 6;             // segment id (wave-uniform)
    const int nb   = blockIdx.x & (Nn / 64 - 1);   // n-tile 0..31
    const int b    = blockIdx.x >> 5;              // batch 0..7
    const int n    = nb * 64 + lane;

    const float a = 0.99666666666666667f;
    const float c = 0.06666666666666667f;
    // A = a^L via 8 squarings (L = 256 = 2^8)
    float A = a;
#pragma unroll
    for (int i = 0; i < 8; ++i) A = A * A;

    const size_t base = (size_t)b * Tn * Nn + n;
    const int t0 = s * L;
    const float* p = in  + base + (size_t)t0 * Nn;
    float*       q = out + base + (size_t)t0 * Nn;

    // ---------------- Pass A: segment end-state (skip last segment) --------
    float E = 0.0f;
    if (s < SEG - 1) {
        float prev = (t0 == 0) ? 0.0f : p[-(ptrdiff_t)Nn];
        float st = 0.0f;
        float xa[U], xb[U];
#pragma unroll
        for (int u = 0; u < U; ++u) xa[u] = p[(size_t)u * Nn];
        for (int tt = 0; tt < L; tt += 2 * U) {
#pragma unroll
            for (int u = 0; u < U; ++u) xb[u] = p[(size_t)(tt + U + u) * Nn];
#pragma unroll
            for (int u = 0; u < U; ++u) {
                float x = xa[u];
                st = fmaf(a, st, c * fabsf(x - prev));
                prev = x;
            }
            if (tt + 2 * U < L) {
#pragma unroll
                for (int u = 0; u < U; ++u) xa[u] = p[(size_t)(tt + 2 * U + u) * Nn];
            }
#pragma unroll
            for (int u = 0; u < U; ++u) {
                float x = xb[u];
                st = fmaf(a, st, c * fabsf(x - prev));
                prev = x;
            }
        }
        E = st;
    }

    __shared__ float lds_E[SEG][64];
    lds_E[s][lane] = E;
    __syncthreads();

    // carry = S_{s-1} = sum_{j<s} E_j * A^(s-1-j), serial combine (<=15 iters,
    // wave-uniform trip count, lane-contiguous LDS reads -> conflict-free)
    float carry = 0.0f;
    for (int j = 0; j < s; ++j) carry = fmaf(A, carry, lds_E[j][lane]);

    // ---------------- Pass B: exact recurrence from carry, write out -------
    {
        float prev = (t0 == 0) ? 0.0f : p[-(ptrdiff_t)Nn];
        float st = carry;
        float xa[U], xb[U];
#pragma unroll
        for (int u = 0; u < U; ++u) xa[u] = p[(size_t)u * Nn];
        for (int tt = 0; tt < L; tt += 2 * U) {
#pragma unroll
            for (int u = 0; u < U; ++u) xb[u] = p[(size_t)(tt + U + u) * Nn];
#pragma unroll
            for (int u = 0; u < U; ++u) {
                float x = xa[u];
                st = fmaf(a, st, c * fabsf(x - prev));
                prev = x;
                xa[u] = st;
            }
#pragma unroll
            for (int u = 0; u < U; ++u)
                __builtin_nontemporal_store(xa[u], q + (size_t)(tt + u) * Nn);
            if (tt + 2 * U < L) {
#pragma unroll
                for (int u = 0; u < U; ++u) xa[u] = p[(size_t)(tt + 2 * U + u) * Nn];
            }
#pragma unroll
            for (int u = 0; u < U; ++u) {
                float x = xb[u];
                st = fmaf(a, st, c * fabsf(x - prev));
                prev = x;
                xb[u] = st;
            }
#pragma unroll
            for (int u = 0; u < U; ++u)
                __builtin_nontemporal_store(xb[u], q + (size_t)(tt + U + u) * Nn);
        }
    }
}

extern "C" void kernel_launch(void* const* d_in, const int* in_sizes, int n_in,
                              void* d_out, int out_size, void* d_ws, size_t ws_size,
                              hipStream_t stream) {
    const float* in = (const float*)d_in[0];
    float* out = (float*)d_out;

    dim3 grid(Bb * (Nn / 64)), block(64 * SEG);   // 256 blocks x 1024 threads
    hipLaunchKernelGGL(ra_filter2_kernel, grid, block, 0, stream, in, out);
}